// Round 1
// baseline (1002.046 us; speedup 1.0000x reference)
//
#include <hip/hip_runtime.h>

#define NN   25000
#define EE   400000
#define FIN  256
#define CC   32
#define AA   9
#define WN   288   // CC*AA
#define BB   8
#define HH   64
#define SS   4
#define FOUT 256

__device__ __forceinline__ float silu_f(float v){ return v / (1.0f + __expf(-v)); }

// ---------------- h = (x @ W1) * (1/sqrt(16)) : [N, 32] ----------------
__global__ __launch_bounds__(256) void k_h(const float* __restrict__ x,
                                           const float* __restrict__ W1,
                                           float* __restrict__ h){
  int gid = blockIdx.x * 256 + threadIdx.x;   // N*CC threads exactly
  int n = gid >> 5, c = gid & 31;
  const float* xr = x + (size_t)n * FIN;
  float acc = 0.f;
  #pragma unroll 8
  for (int f = 0; f < FIN; ++f) acc = fmaf(xr[f], W1[f * CC + c], acc);
  h[gid] = acc * 0.25f;
}

// ---------------- sc_out = (x ⊗ node_attrs) @ Wsc : [N, 256] ----------------
// 64x64 tile, BK=32, 4x4 register tile per thread. A built on the fly.
__global__ __launch_bounds__(256) void k_sc(const float* __restrict__ x,
                                            const float* __restrict__ na,
                                            const float* __restrict__ Wsc,
                                            float* __restrict__ out){
  __shared__ float As[32][64];
  __shared__ float Bs[32][64];
  const int row0 = blockIdx.x * 64;
  const int col0 = blockIdx.y * 64;
  const int tid = threadIdx.x;
  const int tm = tid >> 4, tn = tid & 15;
  float acc[4][4] = {};
  for (int kc = 0; kc < FIN * SS; kc += 32){
    #pragma unroll
    for (int t = 0; t < 8; ++t){
      int idx = tid + t * 256;
      int m = idx & 63, kk = idx >> 6;
      int n = row0 + m;
      int k = kc + kk;
      float v = 0.f;
      if (n < NN) v = x[(size_t)n * FIN + (k >> 2)] * na[n * SS + (k & 3)];
      As[kk][m] = v;
    }
    #pragma unroll
    for (int t = 0; t < 8; ++t){
      int idx = tid + t * 256;
      int o = idx & 63, kk = idx >> 6;
      Bs[kk][o] = Wsc[(size_t)(kc + kk) * FOUT + col0 + o];
    }
    __syncthreads();
    #pragma unroll
    for (int kk = 0; kk < 32; ++kk){
      float4 av = *(const float4*)&As[kk][tm * 4];
      float4 bv = *(const float4*)&Bs[kk][tn * 4];
      float a[4] = {av.x, av.y, av.z, av.w};
      float b[4] = {bv.x, bv.y, bv.z, bv.w};
      #pragma unroll
      for (int i = 0; i < 4; ++i)
        #pragma unroll
        for (int j = 0; j < 4; ++j)
          acc[i][j] = fmaf(a[i], b[j], acc[i][j]);
    }
    __syncthreads();
  }
  #pragma unroll
  for (int i = 0; i < 4; ++i){
    int n = row0 + tm * 4 + i;
    if (n < NN){
      float4 v = {acc[i][0], acc[i][1], acc[i][2], acc[i][3]};
      *(float4*)&out[(size_t)n * FOUT + col0 + tn * 4] = v;
    }
  }
}

// ---------------- fused edge MLP + tensor product + atomic scatter ----------------
// One block = 32 edges. t1=silu(ee@Wm1), t2=silu(t1@Wm2), w=t2@Wm3,
// msg = w * h[src,c] * sh[e,a], atomicAdd into agg[dst].
__global__ __launch_bounds__(256) void k_edge(const float* __restrict__ eemb,
                                              const float* __restrict__ sh,
                                              const int* __restrict__ eidx,
                                              const float* __restrict__ h,
                                              const float* __restrict__ Wm1,
                                              const float* __restrict__ Wm2,
                                              const float* __restrict__ Wm3,
                                              float* __restrict__ agg){
  __shared__ float ee_s[32][8];
  __shared__ float sh_s[32][9];
  __shared__ float hs_s[32][32];
  __shared__ int   dst_s[32];
  __shared__ int   src_s[32];
  __shared__ float t1_s[64][36];   // [h][edge], padded stride 36 (bank spread + 16B align)
  __shared__ float t2_s[64][36];
  __shared__ float w3_s[16 * WN];  // 16-row chunk of Wm3
  const int tid = threadIdx.x;
  const int e0 = blockIdx.x * 32;

  if (tid < 32){
    dst_s[tid] = eidx[e0 + tid];
    src_s[tid] = eidx[EE + e0 + tid];
  }
  __syncthreads();
  { int e = tid >> 3, b = tid & 7; ee_s[e][b] = eemb[(size_t)(e0 + e) * BB + b]; }
  for (int idx = tid; idx < 32 * AA; idx += 256){
    int e = idx / 9, a = idx - e * 9;
    sh_s[e][a] = sh[(size_t)(e0 + e) * AA + a];
  }
  #pragma unroll
  for (int r = 0; r < 4; ++r){
    int idx = tid + r * 256;
    int e = idx >> 5, c = idx & 31;
    hs_s[e][c] = h[(size_t)src_s[e] * CC + c];
  }
  __syncthreads();

  // layer 1: [32,8]@[8,64] -> t1
  {
    const int j = tid & 63, eg = tid >> 6;
    float acc[8] = {};
    #pragma unroll
    for (int b = 0; b < 8; ++b){
      float wv = Wm1[b * HH + j];
      #pragma unroll
      for (int e8 = 0; e8 < 8; ++e8) acc[e8] = fmaf(ee_s[eg * 8 + e8][b], wv, acc[e8]);
    }
    #pragma unroll
    for (int e8 = 0; e8 < 8; ++e8) t1_s[j][eg * 8 + e8] = silu_f(acc[e8]);
  }
  __syncthreads();

  // layer 2: [32,64]@[64,64] -> t2
  {
    const int j = tid & 63, eg = tid >> 6;
    float acc[8] = {};
    for (int hh = 0; hh < 64; ++hh){
      float wv = Wm2[hh * HH + j];
      float a[8];
      *(float4*)&a[0] = *(const float4*)&t1_s[hh][eg * 8];
      *(float4*)&a[4] = *(const float4*)&t1_s[hh][eg * 8 + 4];
      #pragma unroll
      for (int e8 = 0; e8 < 8; ++e8) acc[e8] = fmaf(a[e8], wv, acc[e8]);
    }
    #pragma unroll
    for (int e8 = 0; e8 < 8; ++e8) t2_s[j][eg * 8 + e8] = silu_f(acc[e8]);
  }

  // layer 3 + TP + scatter: thread = (te 0..7 -> 4 edges, tj 0..31 -> cols tj+32m)
  {
    const int tj = tid & 31, te = tid >> 5;
    float acc[4][9] = {};
    for (int hc = 0; hc < 4; ++hc){
      __syncthreads();   // also covers t2 store at hc=0
      #pragma unroll
      for (int t = 0; t < 18; ++t){
        int idx = tid + t * 256;
        w3_s[idx] = Wm3[(size_t)(hc * 16) * WN + idx];
      }
      __syncthreads();
      #pragma unroll
      for (int hh = 0; hh < 16; ++hh){
        float4 av = *(const float4*)&t2_s[hc * 16 + hh][te * 4];
        float a[4] = {av.x, av.y, av.z, av.w};
        #pragma unroll
        for (int m = 0; m < 9; ++m){
          float wv = w3_s[hh * WN + tj + 32 * m];
          #pragma unroll
          for (int i = 0; i < 4; ++i) acc[i][m] = fmaf(a[i], wv, acc[i][m]);
        }
      }
    }
    #pragma unroll
    for (int i = 0; i < 4; ++i){
      int e = te * 4 + i;
      int d = dst_s[e];
      #pragma unroll
      for (int m = 0; m < 9; ++m){
        int j = tj + 32 * m;
        int c = j / 9, a_ = j - c * 9;
        float msg = acc[i][m] * hs_s[e][c] * sh_s[e][a_];
        atomicAdd(&agg[(size_t)d * WN + j], msg);
      }
    }
  }
}

// ---------------- out = silu(agg @ W2) + sc_out ----------------
__global__ __launch_bounds__(256) void k_out(const float* __restrict__ agg,
                                             const float* __restrict__ W2,
                                             float* __restrict__ out){
  __shared__ float As[32][64];
  __shared__ float Bs[32][64];
  const int row0 = blockIdx.x * 64;
  const int col0 = blockIdx.y * 64;
  const int tid = threadIdx.x;
  const int tm = tid >> 4, tn = tid & 15;
  float acc[4][4] = {};
  for (int kc = 0; kc < WN; kc += 32){
    #pragma unroll
    for (int t = 0; t < 8; ++t){
      int idx = tid + t * 256;
      int m = idx & 63, kk = idx >> 6;
      int n = row0 + m;
      float v = 0.f;
      if (n < NN) v = agg[(size_t)n * WN + kc + kk];
      As[kk][m] = v;
    }
    #pragma unroll
    for (int t = 0; t < 8; ++t){
      int idx = tid + t * 256;
      int o = idx & 63, kk = idx >> 6;
      Bs[kk][o] = W2[(size_t)(kc + kk) * FOUT + col0 + o];
    }
    __syncthreads();
    #pragma unroll
    for (int kk = 0; kk < 32; ++kk){
      float4 av = *(const float4*)&As[kk][tm * 4];
      float4 bv = *(const float4*)&Bs[kk][tn * 4];
      float a[4] = {av.x, av.y, av.z, av.w};
      float b[4] = {bv.x, bv.y, bv.z, bv.w};
      #pragma unroll
      for (int i = 0; i < 4; ++i)
        #pragma unroll
        for (int j = 0; j < 4; ++j)
          acc[i][j] = fmaf(a[i], b[j], acc[i][j]);
    }
    __syncthreads();
  }
  #pragma unroll
  for (int i = 0; i < 4; ++i){
    int n = row0 + tm * 4 + i;
    if (n < NN){
      float4 sc = *(const float4*)&out[(size_t)n * FOUT + col0 + tn * 4];
      float4 v;
      v.x = silu_f(acc[i][0]) + sc.x;
      v.y = silu_f(acc[i][1]) + sc.y;
      v.z = silu_f(acc[i][2]) + sc.z;
      v.w = silu_f(acc[i][3]) + sc.w;
      *(float4*)&out[(size_t)n * FOUT + col0 + tn * 4] = v;
    }
  }
}

extern "C" void kernel_launch(void* const* d_in, const int* in_sizes, int n_in,
                              void* d_out, int out_size, void* d_ws, size_t ws_size,
                              hipStream_t stream){
  const float* x    = (const float*)d_in[0];
  const float* na   = (const float*)d_in[1];
  const float* eemb = (const float*)d_in[2];
  const float* shp  = (const float*)d_in[3];
  const int*   eidx = (const int*)d_in[4];
  const float* W1   = (const float*)d_in[5];
  const float* Wm1  = (const float*)d_in[6];
  const float* Wm2  = (const float*)d_in[7];
  const float* Wm3  = (const float*)d_in[8];
  const float* W2   = (const float*)d_in[9];
  const float* Wsc  = (const float*)d_in[10];
  float* out  = (float*)d_out;
  float* agg  = (float*)d_ws;                    // [N, 288]
  float* hbuf = agg + (size_t)NN * WN;           // [N, 32]

  hipMemsetAsync(agg, 0, (size_t)NN * WN * sizeof(float), stream);
  k_h  <<<dim3(NN * CC / 256), dim3(256), 0, stream>>>(x, W1, hbuf);
  k_sc <<<dim3((NN + 63) / 64, FOUT / 64), dim3(256), 0, stream>>>(x, na, Wsc, out);
  k_edge<<<dim3(EE / 32), dim3(256), 0, stream>>>(eemb, shp, eidx, hbuf, Wm1, Wm2, Wm3, agg);
  k_out<<<dim3((NN + 63) / 64, FOUT / 64), dim3(256), 0, stream>>>(agg, W2, out);
}